// Round 15
// baseline (127.147 us; speedup 1.0000x reference)
//
#include <hip/hip_runtime.h>

// IDMForwardSim R15 = R13 (best, 114.4us) + k-slot-permuted x layout making
// the x stream truly NT-safe (R14's NT-x regressed: lane(lk) 16B pairs
// interleave within 64B lines across TWO instructions -> NT refetch).
// Permutation k = s*32 + (j>>2)*16 + lk*4 + (j&3), applied to BOTH the
// A-loads and the B-pack: instr 1 covers whole lines (f32x4 s*8+lk), instr 2
// the next lines (s*8+4+lk). NT criterion holds -> NT x.
// Lessons: fusion +15-17us (R5/R6/R12); NT on reuse -65us (R9) / -8us (R14);
// NT on zero-reuse -17us (R13); write-time compaction -18us (R11).

#define TT 40
#define DD 128
#define ACT_CLIP 3.5f
#define ATT_TEMP 5.0f

typedef short short8 __attribute__((ext_vector_type(8)));
typedef float f32x4 __attribute__((ext_vector_type(4)));

__device__ __forceinline__ unsigned int bf16_rne(float v) {
    unsigned int u = __float_as_uint(v);
    return (u + 0x7FFFu + ((u >> 16) & 1u)) >> 16;
}

// ---------------------------------------------------------------------------
// Kernel 1: pack Wc (128x48, zero-padded cols 40..47) as MFMA B-fragments.
// Record (s,n,h): s=k-step(0..3), n=n-tile(0..2), h=0 hi/1 lo. 64 lanes x 16B.
// PERMUTED slot map: element j of lane l: k = s*32 + (j>>2)*16 + (l>>4)*4
// + (j&3); col = n*16 + (l&15). Must match matvec's A-load layout.
// ---------------------------------------------------------------------------
__global__ __launch_bounds__(256) void precompute_pack(
    const float* __restrict__ W1, const float* __restrict__ b1,
    const float* __restrict__ W2, const float* __restrict__ b2,
    unsigned int* __restrict__ wpack,   // 1536 * 16B records
    float* __restrict__ bcp)            // 48 floats
{
    int idx = blockIdx.x * 256 + threadIdx.x;
    if (idx < 1536) {
        int l   = idx & 63;
        int rec = idx >> 6;           // ((s*3+n)*2+h)
        int h   = rec & 1;
        int sn  = rec >> 1;           // s*3+n
        int n   = sn % 3, s = sn / 3;
        int col = n * 16 + (l & 15);
        int lkb = l >> 4;
        unsigned short hv[8];
#pragma unroll
        for (int j = 0; j < 8; ++j) {
            float v = 0.0f;
            if (col < TT) {
                int k = s * 32 + ((j >> 2) << 4) + lkb * 4 + (j & 3);
                for (int m = 0; m < 100; ++m)
                    v = fmaf(W1[k * 100 + m], W2[m * TT + col], v);
            }
            unsigned int hi = bf16_rne(v);
            float hif = __uint_as_float(hi << 16);
            unsigned int lo = bf16_rne(v - hif);
            hv[j] = (unsigned short)(h == 0 ? hi : lo);
        }
        uint4 o;
        o.x = hv[0] | ((unsigned)hv[1] << 16);
        o.y = hv[2] | ((unsigned)hv[3] << 16);
        o.z = hv[4] | ((unsigned)hv[5] << 16);
        o.w = hv[6] | ((unsigned)hv[7] << 16);
        reinterpret_cast<uint4*>(wpack)[idx] = o;
    } else if (idx < 1536 + 48) {
        int t = idx - 1536;
        float v = 0.0f;
        if (t < TT) {
            v = b2[t];
            for (int m = 0; m < 100; ++m)
                v = fmaf(b1[m], W2[m * TT + t], v);
        }
        bcp[t] = v;
    }
}

// ---------------------------------------------------------------------------
// Kernel 2: att = sigmoid(5*(x@Wc+bc)). Block 256 = 4 waves, 64 rows/block.
// wpack staged to LDS once; x read NT via the permuted slot map:
// instr covers f32x4 s*8+lk (whole 64B lines, same instruction) then s*8+4+lk.
// ---------------------------------------------------------------------------
__global__ __launch_bounds__(256, 4) void matvec_att(
    const float* __restrict__ x,
    const unsigned int* __restrict__ wpack,
    const float* __restrict__ bcp,
    float* __restrict__ attout)          // = d_out + B*TT
{
    __shared__ unsigned int swp[6144];   // 24576 B
    __shared__ float sbc[48];
    __shared__ float satt[64 * TT];      // 10240 B

    int tid = threadIdx.x;
    {
        const uint4* src = reinterpret_cast<const uint4*>(wpack);
        uint4* dst = reinterpret_cast<uint4*>(swp);
#pragma unroll
        for (int i = 0; i < 6; ++i) dst[tid + 256 * i] = src[tid + 256 * i];
        if (tid < 48) sbc[tid] = bcp[tid];
    }
    __syncthreads();

    int wave = tid >> 6, lane = tid & 63;
    int l15 = lane & 15, lk = lane >> 4;
    size_t blk = blockIdx.x;
    size_t row0 = blk * 64 + wave * 16 + l15;   // A-row of lane
    const f32x4* xr = reinterpret_cast<const f32x4*>(x + row0 * DD);

    // permuted A-fragment: j=0..3 -> f32x4[s*8+lk], j=4..7 -> f32x4[s*8+4+lk]
    f32x4 xv[8];
#pragma unroll
    for (int s = 0; s < 4; ++s) {
        xv[2 * s]     = __builtin_nontemporal_load(xr + s * 8 + lk);
        xv[2 * s + 1] = __builtin_nontemporal_load(xr + s * 8 + 4 + lk);
    }

    f32x4 acc[3] = {f32x4{0,0,0,0}, f32x4{0,0,0,0}, f32x4{0,0,0,0}};

#pragma unroll
    for (int s = 0; s < 4; ++s) {
        float fs[8] = {xv[2*s].x, xv[2*s].y, xv[2*s].z, xv[2*s].w,
                       xv[2*s+1].x, xv[2*s+1].y, xv[2*s+1].z, xv[2*s+1].w};
        union { unsigned int u[4]; short8 v; } ah, al;
#pragma unroll
        for (int p = 0; p < 4; ++p) {
            // truncation split: hi = chop16(x); lo = chop16(x - hi);
            // al*bh MFMA term corrects the residual (<=2^-16 rel err).
            unsigned int u0 = __float_as_uint(fs[2*p]);
            unsigned int u1 = __float_as_uint(fs[2*p+1]);
            ah.u[p] = (u0 >> 16) | (u1 & 0xFFFF0000u);
            float r0 = fs[2*p]   - __uint_as_float(u0 & 0xFFFF0000u);
            float r1 = fs[2*p+1] - __uint_as_float(u1 & 0xFFFF0000u);
            al.u[p] = (__float_as_uint(r0) >> 16) |
                      (__float_as_uint(r1) & 0xFFFF0000u);
        }
#pragma unroll
        for (int n = 0; n < 3; ++n) {
            int base = (s * 3 + n) * 512;   // uints: 2 records x 256 uints
            short8 bh = *reinterpret_cast<const short8*>(&swp[base + lane * 4]);
            short8 bl = *reinterpret_cast<const short8*>(&swp[base + 256 + lane * 4]);
            acc[n] = __builtin_amdgcn_mfma_f32_16x16x32_bf16(ah.v, bh, acc[n], 0, 0, 0);
            acc[n] = __builtin_amdgcn_mfma_f32_16x16x32_bf16(al.v, bh, acc[n], 0, 0, 0);
            acc[n] = __builtin_amdgcn_mfma_f32_16x16x32_bf16(ah.v, bl, acc[n], 0, 0, 0);
        }
    }

    // C/D: col = l15 (+16*n), row = wave*16 + lk*4 + reg
#pragma unroll
    for (int n = 0; n < 3; ++n) {
        int col = n * 16 + l15;
        if (col < TT) {
            float bias = sbc[col];
#pragma unroll
            for (int r = 0; r < 4; ++r) {
                int rowl = wave * 16 + lk * 4 + r;
                float L = acc[n][r] + bias;
                satt[rowl * TT + col] =
                    __builtin_amdgcn_rcpf(1.0f + __expf(-ATT_TEMP * L));
            }
        }
    }
    __syncthreads();

    float4* dst = reinterpret_cast<float4*>(attout + blk * 64 * TT);
    const float4* s4 = reinterpret_cast<const float4*>(satt);
    dst[tid]       = s4[tid];
    dst[tid + 256] = s4[tid + 256];
    if (tid < 128) dst[tid + 512] = s4[tid + 512];   // 640 total
}

// ---------------------------------------------------------------------------
// Kernel 3: IDM epilogue. Block 320 = 5 waves, 32 rows (320 items) / block.
// Stage us via coalesced NT f4 loads -> b32 LDS writes at stride-31 layout
// (gcd(31,32)=1 => conflict-free consume); att/prm cached (reused);
// act stored NT (never re-read).
// ---------------------------------------------------------------------------
__global__ __launch_bounds__(320) void epilogue_k(
    const float* __restrict__ us, const float* __restrict__ prm,
    const float* __restrict__ attg,   // = d_out + B*TT (sigmoided by k2)
    float* __restrict__ act)          // = d_out
{
    __shared__ float sus[320 * 31];   // 39680 B

    int tid = threadIdx.x;
    size_t blk = blockIdx.x;

    // att for this thread's item: issue first, consumed last (cached: L2 hit)
    f32x4 a4 = reinterpret_cast<const f32x4*>(attg)[blk * 320u + tid];

    // ---- stage us chunk: 7 coalesced NT f4 loads -> 28 b32 LDS writes ----
    const f32x4* su = reinterpret_cast<const f32x4*>(us) + blk * 2240u;
#pragma unroll
    for (int i = 0; i < 7; ++i) {
        unsigned f = (unsigned)tid + 320u * i;     // f4 index in chunk
        f32x4 v = __builtin_nontemporal_load(su + f);
        unsigned item = f / 7u;
        unsigned slot = f - item * 7u;             // 0..6
        float* w = &sus[item * 31u + slot * 4u];
        w[0] = v.x; w[1] = v.y; w[2] = v.z; w[3] = v.w;
    }

    // ---- per-row params (10 threads share a row; broadcast loads) ----
    unsigned int row_g = (unsigned)(blk * 320u + tid) / 10u;
    const float* pr = prm + (size_t)row_g * 5u;
    float desired_v    = pr[0];
    float desired_tgap = pr[1];
    float min_jamx     = pr[2];
    float max_act      = pr[3];
    float min_act      = pr[4];

    __syncthreads();

    float inv_dv = __builtin_amdgcn_rcpf(desired_v);
    float coef   = 0.5f / sqrtf(max_act * min_act);

    // ---- consume: 20 conflict-free b32 reads (skip fields 1,4) -------
    const float* fp = &sus[(unsigned)tid * 31u];
    float ares[4];
#pragma unroll
    for (int tt = 0; tt < 4; ++tt) {
        float vel = fp[tt * 7 + 0];
        float dvl = fp[tt * 7 + 2], dxl = fp[tt * 7 + 3];
        float dvm = fp[tt * 7 + 5], dxm = fp[tt * 7 + 6];

        float r  = vel * inv_dv;
        float r2 = r * r;
        float common = 1.0f - r2 * r2;
        float base = fmaf(desired_tgap, vel, min_jamx);
        float gl = fmaf(vel * dvl, coef, base);
        float gm = fmaf(vel * dvm, coef, base);
        float ql = gl * __builtin_amdgcn_rcpf(dxl);
        float qm = gm * __builtin_amdgcn_rcpf(dxm);
        float al = max_act * (common - ql * ql);
        float am = max_act * (common - qm * qm);
        al = fminf(fmaxf(al, -ACT_CLIP), ACT_CLIP);
        am = fminf(fmaxf(am, -ACT_CLIP), ACT_CLIP);
        float a = (tt == 0) ? a4.x : (tt == 1) ? a4.y : (tt == 2) ? a4.z : a4.w;
        ares[tt] = fmaf(a, al - am, am);
    }
    f32x4 res = {ares[0], ares[1], ares[2], ares[3]};
    __builtin_nontemporal_store(res, reinterpret_cast<f32x4*>(act) + blk * 320u + tid);
}

extern "C" void kernel_launch(void* const* d_in, const int* in_sizes, int n_in,
                              void* d_out, int out_size, void* d_ws, size_t ws_size,
                              hipStream_t stream) {
    const float* us  = (const float*)d_in[0];
    const float* prm = (const float*)d_in[1];
    const float* x   = (const float*)d_in[2];
    const float* W1  = (const float*)d_in[3];
    const float* b1  = (const float*)d_in[4];
    const float* W2  = (const float*)d_in[5];
    const float* b2  = (const float*)d_in[6];
    float* out = (float*)d_out;

    int B = in_sizes[1] / 5;                 // 262144

    unsigned int* wpack = (unsigned int*)d_ws;          // 24576 B
    float* bcp = (float*)((char*)d_ws + 24576);         // 192 B

    float* attout = out + (size_t)B * TT;    // att half of d_out

    hipLaunchKernelGGL(precompute_pack, dim3(7), dim3(256), 0, stream,
                       W1, b1, W2, b2, wpack, bcp);
    hipLaunchKernelGGL(matvec_att, dim3(B / 64), dim3(256), 0, stream,
                       x, wpack, bcp, attout);
    // B*10 items, 320/block -> B/32 = 8192 blocks
    hipLaunchKernelGGL(epilogue_k, dim3(B / 32), dim3(320), 0, stream,
                       us, prm, attout, out);
}

// Round 16
// 114.189 us; speedup vs baseline: 1.1135x; 1.1135x over previous
//
#include <hip/hip_runtime.h>

// IDMForwardSim R16 = R13 verbatim (best, 114.4us). Reverted R14/R15 NT-x.
// Final lesson set:
//  - fusion (3 schedules): +15-17us (R5/R6/R12) -> split kernels win
//  - NT loads safe ONLY when one instruction consumes whole 128B sectors
//    with no later re-touch: us stage (-17us, R13) yes; x never (R14/R15:
//    A-fragment layout caps per-instr row coverage at 64B of a 128B sector)
//  - write-time compaction: -18us VALU cost (R11)
//  - stride-31 LDS layout: conflict-free consume (R10)

#define TT 40
#define DD 128
#define ACT_CLIP 3.5f
#define ATT_TEMP 5.0f

typedef short short8 __attribute__((ext_vector_type(8)));
typedef float f32x4 __attribute__((ext_vector_type(4)));

__device__ __forceinline__ unsigned int bf16_rne(float v) {
    unsigned int u = __float_as_uint(v);
    return (u + 0x7FFFu + ((u >> 16) & 1u)) >> 16;
}

// ---------------------------------------------------------------------------
// Kernel 1: pack Wc (128x48, zero-padded cols 40..47) as MFMA B-fragments.
// Record (s,n,h): s=k-step(0..3), n=n-tile(0..2), h=0 hi/1 lo. 64 lanes x 16B.
// Element j of lane l: k = s*32 + (l>>4)*8 + j ; col = n*16 + (l&15).
// ---------------------------------------------------------------------------
__global__ __launch_bounds__(256) void precompute_pack(
    const float* __restrict__ W1, const float* __restrict__ b1,
    const float* __restrict__ W2, const float* __restrict__ b2,
    unsigned int* __restrict__ wpack,   // 1536 * 16B records
    float* __restrict__ bcp)            // 48 floats
{
    int idx = blockIdx.x * 256 + threadIdx.x;
    if (idx < 1536) {
        int l   = idx & 63;
        int rec = idx >> 6;           // ((s*3+n)*2+h)
        int h   = rec & 1;
        int sn  = rec >> 1;           // s*3+n
        int n   = sn % 3, s = sn / 3;
        int col = n * 16 + (l & 15);
        int k0  = s * 32 + (l >> 4) * 8;
        unsigned short hv[8];
#pragma unroll
        for (int j = 0; j < 8; ++j) {
            float v = 0.0f;
            if (col < TT) {
                int k = k0 + j;
                for (int m = 0; m < 100; ++m)
                    v = fmaf(W1[k * 100 + m], W2[m * TT + col], v);
            }
            unsigned int hi = bf16_rne(v);
            float hif = __uint_as_float(hi << 16);
            unsigned int lo = bf16_rne(v - hif);
            hv[j] = (unsigned short)(h == 0 ? hi : lo);
        }
        uint4 o;
        o.x = hv[0] | ((unsigned)hv[1] << 16);
        o.y = hv[2] | ((unsigned)hv[3] << 16);
        o.z = hv[4] | ((unsigned)hv[5] << 16);
        o.w = hv[6] | ((unsigned)hv[7] << 16);
        reinterpret_cast<uint4*>(wpack)[idx] = o;
    } else if (idx < 1536 + 48) {
        int t = idx - 1536;
        float v = 0.0f;
        if (t < TT) {
            v = b2[t];
            for (int m = 0; m < 100; ++m)
                v = fmaf(b1[m], W2[m * TT + t], v);
        }
        bcp[t] = v;
    }
}

// ---------------------------------------------------------------------------
// Kernel 2: att = sigmoid(5*(x@Wc+bc)). Block 256 = 4 waves, 64 rows/block.
// R3-style: wpack staged to LDS once (L2->LDS, then conflict-light b128).
// x loads CACHED (NT unsafe: 64B/instr coverage of 128B sectors, R14/R15).
// ---------------------------------------------------------------------------
__global__ __launch_bounds__(256, 4) void matvec_att(
    const float* __restrict__ x,
    const unsigned int* __restrict__ wpack,
    const float* __restrict__ bcp,
    float* __restrict__ attout)          // = d_out + B*TT
{
    __shared__ unsigned int swp[6144];   // 24576 B
    __shared__ float sbc[48];
    __shared__ float satt[64 * TT];      // 10240 B

    int tid = threadIdx.x;
    {
        const uint4* src = reinterpret_cast<const uint4*>(wpack);
        uint4* dst = reinterpret_cast<uint4*>(swp);
#pragma unroll
        for (int i = 0; i < 6; ++i) dst[tid + 256 * i] = src[tid + 256 * i];
        if (tid < 48) sbc[tid] = bcp[tid];
    }
    __syncthreads();

    int wave = tid >> 6, lane = tid & 63;
    int l15 = lane & 15, lk = lane >> 4;
    size_t blk = blockIdx.x;
    size_t row0 = blk * 64 + wave * 16 + l15;   // A-row of lane
    const float* xr = x + row0 * DD;

    float4 xv[8];
#pragma unroll
    for (int s = 0; s < 4; ++s) {
        xv[2 * s]     = *reinterpret_cast<const float4*>(xr + s * 32 + lk * 8);
        xv[2 * s + 1] = *reinterpret_cast<const float4*>(xr + s * 32 + lk * 8 + 4);
    }

    f32x4 acc[3] = {f32x4{0,0,0,0}, f32x4{0,0,0,0}, f32x4{0,0,0,0}};

#pragma unroll
    for (int s = 0; s < 4; ++s) {
        float fs[8] = {xv[2*s].x, xv[2*s].y, xv[2*s].z, xv[2*s].w,
                       xv[2*s+1].x, xv[2*s+1].y, xv[2*s+1].z, xv[2*s+1].w};
        union { unsigned int u[4]; short8 v; } ah, al;
#pragma unroll
        for (int p = 0; p < 4; ++p) {
            // truncation split: hi = chop16(x); lo = chop16(x - hi);
            // al*bh MFMA term corrects the residual (<=2^-16 rel err).
            unsigned int u0 = __float_as_uint(fs[2*p]);
            unsigned int u1 = __float_as_uint(fs[2*p+1]);
            ah.u[p] = (u0 >> 16) | (u1 & 0xFFFF0000u);
            float r0 = fs[2*p]   - __uint_as_float(u0 & 0xFFFF0000u);
            float r1 = fs[2*p+1] - __uint_as_float(u1 & 0xFFFF0000u);
            al.u[p] = (__float_as_uint(r0) >> 16) |
                      (__float_as_uint(r1) & 0xFFFF0000u);
        }
#pragma unroll
        for (int n = 0; n < 3; ++n) {
            int base = (s * 3 + n) * 512;   // uints: 2 records x 256 uints
            short8 bh = *reinterpret_cast<const short8*>(&swp[base + lane * 4]);
            short8 bl = *reinterpret_cast<const short8*>(&swp[base + 256 + lane * 4]);
            acc[n] = __builtin_amdgcn_mfma_f32_16x16x32_bf16(ah.v, bh, acc[n], 0, 0, 0);
            acc[n] = __builtin_amdgcn_mfma_f32_16x16x32_bf16(al.v, bh, acc[n], 0, 0, 0);
            acc[n] = __builtin_amdgcn_mfma_f32_16x16x32_bf16(ah.v, bl, acc[n], 0, 0, 0);
        }
    }

    // C/D: col = l15 (+16*n), row = wave*16 + lk*4 + reg
#pragma unroll
    for (int n = 0; n < 3; ++n) {
        int col = n * 16 + l15;
        if (col < TT) {
            float bias = sbc[col];
#pragma unroll
            for (int r = 0; r < 4; ++r) {
                int rowl = wave * 16 + lk * 4 + r;
                float L = acc[n][r] + bias;
                satt[rowl * TT + col] =
                    __builtin_amdgcn_rcpf(1.0f + __expf(-ATT_TEMP * L));
            }
        }
    }
    __syncthreads();

    float4* dst = reinterpret_cast<float4*>(attout + blk * 64 * TT);
    const float4* s4 = reinterpret_cast<const float4*>(satt);
    dst[tid]       = s4[tid];
    dst[tid + 256] = s4[tid + 256];
    if (tid < 128) dst[tid + 512] = s4[tid + 512];   // 640 total
}

// ---------------------------------------------------------------------------
// Kernel 3: IDM epilogue. Block 320 = 5 waves, 32 rows (320 items) / block.
// Stage us via coalesced NT f4 loads -> b32 LDS writes at stride-31 layout
// (gcd(31,32)=1 => conflict-free consume); att/prm cached (reused);
// act stored NT (never re-read).
// ---------------------------------------------------------------------------
__global__ __launch_bounds__(320) void epilogue_k(
    const float* __restrict__ us, const float* __restrict__ prm,
    const float* __restrict__ attg,   // = d_out + B*TT (sigmoided by k2)
    float* __restrict__ act)          // = d_out
{
    __shared__ float sus[320 * 31];   // 39680 B

    int tid = threadIdx.x;
    size_t blk = blockIdx.x;

    // att for this thread's item: issue first, consumed last (cached: L2 hit)
    f32x4 a4 = reinterpret_cast<const f32x4*>(attg)[blk * 320u + tid];

    // ---- stage us chunk: 7 coalesced NT f4 loads -> 28 b32 LDS writes ----
    const f32x4* su = reinterpret_cast<const f32x4*>(us) + blk * 2240u;
#pragma unroll
    for (int i = 0; i < 7; ++i) {
        unsigned f = (unsigned)tid + 320u * i;     // f4 index in chunk
        f32x4 v = __builtin_nontemporal_load(su + f);
        unsigned item = f / 7u;
        unsigned slot = f - item * 7u;             // 0..6
        float* w = &sus[item * 31u + slot * 4u];
        w[0] = v.x; w[1] = v.y; w[2] = v.z; w[3] = v.w;
    }

    // ---- per-row params (10 threads share a row; broadcast loads) ----
    unsigned int row_g = (unsigned)(blk * 320u + tid) / 10u;
    const float* pr = prm + (size_t)row_g * 5u;
    float desired_v    = pr[0];
    float desired_tgap = pr[1];
    float min_jamx     = pr[2];
    float max_act      = pr[3];
    float min_act      = pr[4];

    __syncthreads();

    float inv_dv = __builtin_amdgcn_rcpf(desired_v);
    float coef   = 0.5f / sqrtf(max_act * min_act);

    // ---- consume: 20 conflict-free b32 reads (skip fields 1,4) -------
    const float* fp = &sus[(unsigned)tid * 31u];
    float ares[4];
#pragma unroll
    for (int tt = 0; tt < 4; ++tt) {
        float vel = fp[tt * 7 + 0];
        float dvl = fp[tt * 7 + 2], dxl = fp[tt * 7 + 3];
        float dvm = fp[tt * 7 + 5], dxm = fp[tt * 7 + 6];

        float r  = vel * inv_dv;
        float r2 = r * r;
        float common = 1.0f - r2 * r2;
        float base = fmaf(desired_tgap, vel, min_jamx);
        float gl = fmaf(vel * dvl, coef, base);
        float gm = fmaf(vel * dvm, coef, base);
        float ql = gl * __builtin_amdgcn_rcpf(dxl);
        float qm = gm * __builtin_amdgcn_rcpf(dxm);
        float al = max_act * (common - ql * ql);
        float am = max_act * (common - qm * qm);
        al = fminf(fmaxf(al, -ACT_CLIP), ACT_CLIP);
        am = fminf(fmaxf(am, -ACT_CLIP), ACT_CLIP);
        float a = (tt == 0) ? a4.x : (tt == 1) ? a4.y : (tt == 2) ? a4.z : a4.w;
        ares[tt] = fmaf(a, al - am, am);
    }
    f32x4 res = {ares[0], ares[1], ares[2], ares[3]};
    __builtin_nontemporal_store(res, reinterpret_cast<f32x4*>(act) + blk * 320u + tid);
}

extern "C" void kernel_launch(void* const* d_in, const int* in_sizes, int n_in,
                              void* d_out, int out_size, void* d_ws, size_t ws_size,
                              hipStream_t stream) {
    const float* us  = (const float*)d_in[0];
    const float* prm = (const float*)d_in[1];
    const float* x   = (const float*)d_in[2];
    const float* W1  = (const float*)d_in[3];
    const float* b1  = (const float*)d_in[4];
    const float* W2  = (const float*)d_in[5];
    const float* b2  = (const float*)d_in[6];
    float* out = (float*)d_out;

    int B = in_sizes[1] / 5;                 // 262144

    unsigned int* wpack = (unsigned int*)d_ws;          // 24576 B
    float* bcp = (float*)((char*)d_ws + 24576);         // 192 B

    float* attout = out + (size_t)B * TT;    // att half of d_out

    hipLaunchKernelGGL(precompute_pack, dim3(7), dim3(256), 0, stream,
                       W1, b1, W2, b2, wpack, bcp);
    hipLaunchKernelGGL(matvec_att, dim3(B / 64), dim3(256), 0, stream,
                       x, wpack, bcp, attout);
    // B*10 items, 320/block -> B/32 = 8192 blocks
    hipLaunchKernelGGL(epilogue_k, dim3(B / 32), dim3(320), 0, stream,
                       us, prm, attout, out);
}